// Round 26
// baseline (72.809 us; speedup 1.0000x reference)
//
#include <hip/hip_runtime.h>

#define MD   4
#define B_   4
#define C_   128
#define H_   128
#define W_   256
#define ND   9

typedef float  float4v __attribute__((ext_vector_type(4)));
typedef float  f32x4   __attribute__((ext_vector_type(4)));
typedef short  bf16x8  __attribute__((ext_vector_type(8)));
typedef unsigned int u32;
typedef u32    u32x4   __attribute__((ext_vector_type(4)));

#define TS ((size_t)B_ * H_ * 4 * W_ * 32)   // halfs in converted t2

static __device__ __forceinline__ unsigned short f2bf(float f) {
    u32 u = __float_as_uint(f);
    u32 r = (u + 0x7fffu + ((u >> 16) & 1u)) >> 16;   // RNE
    return (unsigned short)r;
}

// ---- pass 1: t2 only -> bf16 ws (R19-exact body; L3-resident source) ----
__global__ __launch_bounds__(256, 2)
void convert_one(const float* __restrict__ src0,
                 unsigned short* __restrict__ dst0) {
    const int bid = blockIdx.x;          // [1:0]=kc [8:2]=y [10:9]=b
    const int kc  = bid & 3;
    const int y   = (bid >> 2) & (H_ - 1);
    const int b   = bid >> 9;
    const int x   = threadIdx.x;         // 0..255
    const float* src = src0 + ((size_t)(b * C_ + kc * 32) * H_ + y) * W_ + x;
    const size_t hw = (size_t)H_ * W_;

    float f[32];
    #pragma unroll
    for (int k = 0; k < 32; ++k) f[k] = src[(size_t)k * hw];

    unsigned short* dst =
        dst0 + ((((size_t)(b * H_ + y)) * 4 + kc) * W_ + x) * 32;
    #pragma unroll
    for (int q = 0; q < 4; ++q) {
        u32x4 pk;
        #pragma unroll
        for (int j = 0; j < 4; ++j)
            pk[j] = (u32)f2bf(f[q * 8 + 2 * j]) |
                    ((u32)f2bf(f[q * 8 + 2 * j + 1]) << 16);
        *(u32x4*)(dst + q * 8) = pk;
    }
}

// ---- pass 2: banded-Gram MFMA, minimal VMEM instruction count ----
// Model (4-kernel confirmed): dur ~= 0.29us x per-wave VMEM instrs.
// A: x-vectorized cooperative load (4 dwordx4/thread/chunk) + LDS
//    transpose -> 16 instrs/wave (was 64 dwords).
// B: verbatim 80 b128/wave from t2 ws.
// Stores: band staged to LDS, 1 exec-masked b128 store per r -> 18
//    (was 54 dwords). Total 114 vs mfma3/7's 198, mfma5's 142.
__global__ __launch_bounds__(512, 2)
void corr_mfma8(const float* __restrict__ t1,
                const unsigned short* __restrict__ t2w,
                float* __restrict__ out) {
    __shared__ u32   aS[2][128][20];           // 2y x 128x x (16 c-pair + pad) = 40960 B
    __shared__ float scr[8][16 * 36 + 9 * 16]; // per wave: band 576 + sb 144  = 23040 B

    const int tid = threadIdx.x;
    const int l   = tid & 63;
    const int w   = tid >> 6;                  // 0..7
    const int bid = blockIdx.x;                // 512 blocks
    const int xcd = bid & 7;                   // 2-D XCD tiling
    const int xh  = xcd >> 2;                  // x half
    const int ypq = xcd & 3;                   // y-pair quarter
    const int rst = bid >> 3;                  // 0..63
    const int b   = rst >> 4;
    const int yp  = ypq * 16 + (rst & 15);
    const int y0  = yp * 2;
    const int ln  = l & 15;
    const int kg  = l >> 4;                    // 0..3
    const int X0  = (xh * 8 + w) * 16;         // this wave's x-tile
    const float scale = 1.0f / (float)C_;
    const bf16x8 z8 = (bf16x8)(short)0;
    const size_t hw = (size_t)H_ * W_;

    // A-staging identity: thread -> (c-pair, y-sel, x-octet)
    const int cpair = tid & 15;
    const int ys    = (tid >> 4) & 1;
    const int xoct  = tid >> 5;                // 0..15
    const int gx    = xh * 128 + xoct * 8;

    float fst[16];                             // [c_even j0..7 | c_odd j0..7]
#define ALOAD(kc_)                                                         \
    {                                                                      \
        const float* s0 = t1 + ((size_t)(b * C_ + (kc_) * 32 + 2 * cpair)  \
                                * H_ + y0 + ys) * W_ + gx;                 \
        const float* s1 = s0 + hw;                                         \
        *(float4v*)&fst[0]  = *(const float4v*)(s0);                       \
        *(float4v*)&fst[4]  = *(const float4v*)(s0 + 4);                   \
        *(float4v*)&fst[8]  = *(const float4v*)(s1);                       \
        *(float4v*)&fst[12] = *(const float4v*)(s1 + 4);                   \
    }
#define AWRITE()                                                           \
    {                                                                      \
        _Pragma("unroll")                                                  \
        for (int j = 0; j < 8; ++j) {                                      \
            const u32 pk = (u32)f2bf(fst[j]) |                             \
                           ((u32)f2bf(fst[8 + j]) << 16);                  \
            aS[ys][xoct * 8 + j][cpair] = pk;                              \
        }                                                                  \
    }

    f32x4 aA0[ND], aA1[ND], aB0[ND], aB1[ND];
    #pragma unroll
    for (int r = 0; r < ND; ++r) {
        aA0[r] = (f32x4)0.0f; aA1[r] = (f32x4)0.0f;
        aB0[r] = (f32x4)0.0f; aB1[r] = (f32x4)0.0f;
    }

    int col0 = X0 - 8 + ln;                    // B-tile 0 column (this lane)
    int col1 = X0 + 8 + ln;                    // B-tile 1 column
    const bool ob0 = col0 < 0;
    const bool ob1 = col1 > W_ - 1;
    col0 = ob0 ? 0 : col0;
    col1 = ob1 ? W_ - 1 : col1;

    ALOAD(0); AWRITE();
    __syncthreads();                           // chunk 0 staged

    #pragma unroll
    for (int kc = 0; kc < 4; ++kc) {
        // A fragments from LDS: u32s cpair kg*4..+4 = channels kg*8..+8
        const bf16x8 fA = *(const bf16x8*)&aS[0][w * 16 + ln][kg * 4];
        const bf16x8 fB = *(const bf16x8*)&aS[1][w * 16 + ln][kg * 4];
        if (kc < 3) ALOAD(kc + 1);             // next slab in flight

        #pragma unroll
        for (int r = 0; r < ND + 1; ++r) {     // staged rows y0-4 .. y0+5
            const int row = y0 + r - MD;       // wave-uniform
            if (0 <= row && row < H_) {
                const unsigned short* b_base =
                    t2w + ((((size_t)(b * H_ + row)) * 4 + kc) * W_) * 32;
                bf16x8 b0 = *(const bf16x8*)(b_base + (size_t)col0 * 32 + kg * 8);
                bf16x8 b1 = *(const bf16x8*)(b_base + (size_t)col1 * 32 + kg * 8);
                b0 = ob0 ? z8 : b0;            // zero-pad OOB x'
                b1 = ob1 ? z8 : b1;
                if (r < ND) {                  // feeds y0, dy=r
                    aA0[r] = __builtin_amdgcn_mfma_f32_16x16x32_bf16(fA, b0, aA0[r], 0, 0, 0);
                    aA1[r] = __builtin_amdgcn_mfma_f32_16x16x32_bf16(fA, b1, aA1[r], 0, 0, 0);
                }
                if (r >= 1) {                  // feeds y0+1, dy=r-1
                    aB0[r-1] = __builtin_amdgcn_mfma_f32_16x16x32_bf16(fB, b0, aB0[r-1], 0, 0, 0);
                    aB1[r-1] = __builtin_amdgcn_mfma_f32_16x16x32_bf16(fB, b1, aB1[r-1], 0, 0, 0);
                }
            }
        }

        __syncthreads();                       // all waves done reading aS
        if (kc < 3) { AWRITE(); }
        __syncthreads();                       // next slab visible
    }
#undef ALOAD
#undef AWRITE

    float* sw = scr[w];                        // band: [16 m][36 cols]
    float* sb = sw + 16 * 36;                  // store stage: [9 dx][16 m]

    // ---- extraction pass 1: y0 ----
    // T0 parked at cols 0..15, T1 at 16..31 -> T1 col0 = window col 16,
    // so the band gather is branchless: sw[m*36 + md + 4].
    #pragma unroll
    for (int r = 0; r < ND; ++r) {
        const int row = y0 + r - MD;
        const bool liv = (0 <= row && row < H_);
        #pragma unroll
        for (int i = 0; i < 4; ++i) {
            sw[(kg * 4 + i) * 36 + ln]      = aA0[r][i];
            sw[(kg * 4 + i) * 36 + 16 + ln] = aA1[r][i];
        }
        #pragma unroll
        for (int i = 0; i < 3; ++i) {
            const int dx = i * 4 + kg;
            if (dx < ND) {
                const float v = liv ? sw[ln * 36 + ln + dx + 4] * scale : 0.0f;
                sb[dx * 16 + ln] = v;
            }
        }
        if (l < 36) {                          // 1 b128 store per r
            const int dxs = l >> 2, mq = l & 3;
            const float4v v4 = *(const float4v*)&sb[dxs * 16 + mq * 4];
            *(float4v*)&out[((((size_t)b * 81) + r * ND + dxs) * H_ + y0) * W_
                            + X0 + mq * 4] = v4;
        }
    }
    // ---- extraction pass 2: y0+1 ----
    #pragma unroll
    for (int r = 0; r < ND; ++r) {
        const int row = y0 + 1 + r - MD;
        const bool liv = (0 <= row && row < H_);
        #pragma unroll
        for (int i = 0; i < 4; ++i) {
            sw[(kg * 4 + i) * 36 + ln]      = aB0[r][i];
            sw[(kg * 4 + i) * 36 + 16 + ln] = aB1[r][i];
        }
        #pragma unroll
        for (int i = 0; i < 3; ++i) {
            const int dx = i * 4 + kg;
            if (dx < ND) {
                const float v = liv ? sw[ln * 36 + ln + dx + 4] * scale : 0.0f;
                sb[dx * 16 + ln] = v;
            }
        }
        if (l < 36) {
            const int dxs = l >> 2, mq = l & 3;
            const float4v v4 = *(const float4v*)&sb[dxs * 16 + mq * 4];
            *(float4v*)&out[((((size_t)b * 81) + r * ND + dxs) * H_ + (y0 + 1)) * W_
                            + X0 + mq * 4] = v4;
        }
    }
}

// ---- fallback: proven 76us scalar kernel (R11) if ws too small ----
__global__ __launch_bounds__(9 * 64, 3)
void corr_fallback(const float* __restrict__ t1,
                   const float* __restrict__ t2,
                   float* __restrict__ out) {
    const int tid  = threadIdx.x;
    const int lane = tid & 63;
    const int w    = tid >> 6;
    const int bid  = blockIdx.x;
    const int swz  = (bid & 7) * 32 + (bid >> 3);
    const int yp   = swz & 63;
    const int b    = swz >> 6;
    const int y0   = yp * 2;
    const int half = lane >> 5;
    const int lx   = lane & 31;
    const int x0   = lx * 8;
    const int yrow = y0 + half;
    const int yy   = yrow + w - MD;
    const bool live = (0 <= yy) && (yy < H_);
    const int  yc  = yy < 0 ? 0 : (yy > H_ - 1 ? H_ - 1 : yy);
    const float sc = live ? (1.0f / (float)C_) : 0.0f;
    const bool lm  = (lx == 0);
    const bool rm  = (lx == 31);
    const int offL = lm ? 0 : -4;
    const int offR = rm ? 0 :  8;

    float acc[ND][8];
    #pragma unroll
    for (int dx = 0; dx < ND; ++dx)
        #pragma unroll
        for (int j = 0; j < 8; ++j) acc[dx][j] = 0.0f;

    const float* p1 = t1 + (((size_t)(b * C_)) * H_ + yrow) * W_ + x0;
    const float* p2 = t2 + (((size_t)(b * C_)) * H_ + yc  ) * W_ + x0;
    const size_t chstr = (size_t)H_ * W_;

    #pragma unroll 2
    for (int c = 0; c < C_; ++c) {
        const float* pc1 = p1 + (size_t)c * chstr;
        const float* pc2 = p2 + (size_t)c * chstr;
        const float4v a0 = *(const float4v*)(pc1);
        const float4v a1 = *(const float4v*)(pc1 + 4);
        float4v wl = *(const float4v*)(pc2 + offL);
        const float4v v0 = *(const float4v*)(pc2);
        const float4v v1 = *(const float4v*)(pc2 + 4);
        float4v wr = *(const float4v*)(pc2 + offR);
        #pragma unroll
        for (int qq = 0; qq < 4; ++qq) {
            wl[qq] = lm ? 0.0f : wl[qq];
            wr[qq] = rm ? 0.0f : wr[qq];
        }
        float win[16];
        #pragma unroll
        for (int qq = 0; qq < 4; ++qq) {
            win[qq] = wl[qq]; win[4 + qq] = v0[qq];
            win[8 + qq] = v1[qq]; win[12 + qq] = wr[qq];
        }
        #pragma unroll
        for (int dx = 0; dx < ND; ++dx)
            #pragma unroll
            for (int j = 0; j < 8; ++j) {
                const float aj = (j < 4) ? a0[j] : a1[j - 4];
                acc[dx][j] = fmaf(aj, win[dx + j], acc[dx][j]);
            }
    }

    #pragma unroll
    for (int dx = 0; dx < ND; ++dx) {
        float4v o0, o1;
        #pragma unroll
        for (int j = 0; j < 4; ++j) {
            o0[j] = acc[dx][j] * sc;
            o1[j] = acc[dx][4 + j] * sc;
        }
        const size_t oidx =
            (((size_t)(b * ND * ND) + w * ND + dx) * H_ + yrow) * W_ + x0;
        *(float4v*)&out[oidx]     = o0;
        *(float4v*)&out[oidx + 4] = o1;
    }
}

extern "C" void kernel_launch(void* const* d_in, const int* in_sizes, int n_in,
                              void* d_out, int out_size, void* d_ws, size_t ws_size,
                              hipStream_t stream) {
    const float* t1 = (const float*)d_in[0];
    const float* t2 = (const float*)d_in[1];
    float* out      = (float*)d_out;
    const size_t need = TS * sizeof(unsigned short);   // 33.5 MB (t2 only)
    if (ws_size >= need) {
        unsigned short* ws = (unsigned short*)d_ws;
        convert_one<<<dim3(B_ * H_ * 4), 256, 0, stream>>>(t2, ws);
        corr_mfma8 <<<dim3(B_ * H_), 512, 0, stream>>>(t1, ws, out);
    } else {
        corr_fallback<<<dim3(B_ * H_ / 2), 9 * 64, 0, stream>>>(t1, t2, out);
    }
}

// Round 27
// 68.212 us; speedup vs baseline: 1.0674x; 1.0674x over previous
//
#include <hip/hip_runtime.h>

#define MD   4
#define B_   4
#define C_   128
#define H_   128
#define W_   256
#define ND   9

typedef float  float4v __attribute__((ext_vector_type(4)));
typedef float  f32x4   __attribute__((ext_vector_type(4)));
typedef short  bf16x8  __attribute__((ext_vector_type(8)));
typedef unsigned int u32;
typedef u32    u32x4   __attribute__((ext_vector_type(4)));

#define TS ((size_t)B_ * H_ * 4 * W_ * 32)   // halfs in converted t2

static __device__ __forceinline__ unsigned short f2bf(float f) {
    u32 u = __float_as_uint(f);
    u32 r = (u + 0x7fffu + ((u >> 16) & 1u)) >> 16;   // RNE
    return (unsigned short)r;
}

// ---- pass 1: t2 only -> bf16 ws (R19-exact body; L3-resident source) ----
__global__ __launch_bounds__(256, 2)
void convert_one(const float* __restrict__ src0,
                 unsigned short* __restrict__ dst0) {
    const int bid = blockIdx.x;          // [1:0]=kc [8:2]=y [10:9]=b
    const int kc  = bid & 3;
    const int y   = (bid >> 2) & (H_ - 1);
    const int b   = bid >> 9;
    const int x   = threadIdx.x;         // 0..255
    const float* src = src0 + ((size_t)(b * C_ + kc * 32) * H_ + y) * W_ + x;
    const size_t hw = (size_t)H_ * W_;

    float f[32];
    #pragma unroll
    for (int k = 0; k < 32; ++k) f[k] = src[(size_t)k * hw];

    unsigned short* dst =
        dst0 + ((((size_t)(b * H_ + y)) * 4 + kc) * W_ + x) * 32;
    #pragma unroll
    for (int q = 0; q < 4; ++q) {
        u32x4 pk;
        #pragma unroll
        for (int j = 0; j < 4; ++j)
            pk[j] = (u32)f2bf(f[q * 8 + 2 * j]) |
                    ((u32)f2bf(f[q * 8 + 2 * j + 1]) << 16);
        *(u32x4*)(dst + q * 8) = pk;
    }
}

// ---- pass 2: banded-Gram MFMA (mfma9) ----
// A-path: VERBATIM mfma3 (57us proven): direct t1 dwords + f2bf inside
// the kc loop, no LDS staging, no barriers.
// Stores: mfma8's refcheck-passed compaction: branchless [16][36] band
// park + sb stage + 1 exec-masked b128 store per r (54 -> 18 instrs).
// Attribution test: mfma7->mfma8 bundled A-transpose AND store changes
// and regressed; this isolates the store change on a clean base.
__global__ __launch_bounds__(512, 2)
void corr_mfma9(const float* __restrict__ t1,
                const unsigned short* __restrict__ t2w,
                float* __restrict__ out) {
    __shared__ float scr[8][16 * 36 + 9 * 16];   // 23040 B

    const int tid = threadIdx.x;
    const int l   = tid & 63;
    const int w   = tid >> 6;                  // 0..7
    const int bid = blockIdx.x;                // 512 blocks
    const int xcd = bid & 7;                   // 2-D XCD tiling
    const int xh  = xcd >> 2;                  // x half
    const int ypq = xcd & 3;                   // y-pair quarter
    const int rst = bid >> 3;                  // 0..63
    const int b   = rst >> 4;
    const int yp  = ypq * 16 + (rst & 15);
    const int y0  = yp * 2;
    const int ln  = l & 15;
    const int kg  = l >> 4;                    // 0..3
    const int X0  = (xh * 8 + w) * 16;         // this wave's x-tile
    const float scale = 1.0f / (float)C_;
    const bf16x8 z8 = (bf16x8)(short)0;
    const size_t hw = (size_t)H_ * W_;

    f32x4 aA0[ND], aA1[ND], aB0[ND], aB1[ND];
    #pragma unroll
    for (int r = 0; r < ND; ++r) {
        aA0[r] = (f32x4)0.0f; aA1[r] = (f32x4)0.0f;
        aB0[r] = (f32x4)0.0f; aB1[r] = (f32x4)0.0f;
    }

    int col0 = X0 - 8 + ln;                    // B-tile 0 column (this lane)
    int col1 = X0 + 8 + ln;                    // B-tile 1 column
    const bool ob0 = col0 < 0;
    const bool ob1 = col1 > W_ - 1;
    col0 = ob0 ? 0 : col0;
    col1 = ob1 ? W_ - 1 : col1;

    #pragma unroll
    for (int kc = 0; kc < 4; ++kc) {
        // A fragments (fp32 direct + in-register bf16 pack) for both y
        const float* aspA =
            t1 + ((size_t)(b * C_ + kc * 32 + kg * 8) * H_ + y0) * W_ + X0 + ln;
        const float* aspB = aspA + W_;         // y0+1
        float avA[8], avB[8];
        #pragma unroll
        for (int j = 0; j < 8; ++j) avA[j] = aspA[(size_t)j * hw];
        #pragma unroll
        for (int j = 0; j < 8; ++j) avB[j] = aspB[(size_t)j * hw];
        bf16x8 fA, fB;
        #pragma unroll
        for (int j = 0; j < 8; ++j) { fA[j] = (short)f2bf(avA[j]);
                                      fB[j] = (short)f2bf(avB[j]); }

        #pragma unroll
        for (int r = 0; r < ND + 1; ++r) {     // staged rows y0-4 .. y0+5
            const int row = y0 + r - MD;       // wave-uniform
            if (0 <= row && row < H_) {
                const unsigned short* b_base =
                    t2w + ((((size_t)(b * H_ + row)) * 4 + kc) * W_) * 32;
                bf16x8 b0 = *(const bf16x8*)(b_base + (size_t)col0 * 32 + kg * 8);
                bf16x8 b1 = *(const bf16x8*)(b_base + (size_t)col1 * 32 + kg * 8);
                b0 = ob0 ? z8 : b0;            // zero-pad OOB x'
                b1 = ob1 ? z8 : b1;
                if (r < ND) {                  // feeds y0, dy=r
                    aA0[r] = __builtin_amdgcn_mfma_f32_16x16x32_bf16(fA, b0, aA0[r], 0, 0, 0);
                    aA1[r] = __builtin_amdgcn_mfma_f32_16x16x32_bf16(fA, b1, aA1[r], 0, 0, 0);
                }
                if (r >= 1) {                  // feeds y0+1, dy=r-1
                    aB0[r-1] = __builtin_amdgcn_mfma_f32_16x16x32_bf16(fB, b0, aB0[r-1], 0, 0, 0);
                    aB1[r-1] = __builtin_amdgcn_mfma_f32_16x16x32_bf16(fB, b1, aB1[r-1], 0, 0, 0);
                }
            }
        }
    }

    float* sw = scr[w];                        // band: [16 m][36 cols]
    float* sb = sw + 16 * 36;                  // store stage: [9 dx][16 m]

    // ---- extraction pass 1: y0 (mfma8-verbatim, refcheck-passed) ----
    // T0 parked at cols 0..15 (x' = X0-8+n), T1 at 16..31 (x' = X0+8+n):
    // out(x=X0+m, dx) -> x' = X0+m+dx-4 -> col m+dx+4. Branchless gather.
    #pragma unroll
    for (int r = 0; r < ND; ++r) {
        const int row = y0 + r - MD;
        const bool liv = (0 <= row && row < H_);
        #pragma unroll
        for (int i = 0; i < 4; ++i) {
            sw[(kg * 4 + i) * 36 + ln]      = aA0[r][i];
            sw[(kg * 4 + i) * 36 + 16 + ln] = aA1[r][i];
        }
        #pragma unroll
        for (int i = 0; i < 3; ++i) {
            const int dx = i * 4 + kg;
            if (dx < ND) {
                const float v = liv ? sw[ln * 36 + ln + dx + 4] * scale : 0.0f;
                sb[dx * 16 + ln] = v;
            }
        }
        if (l < 36) {                          // 1 b128 store per r
            const int dxs = l >> 2, mq = l & 3;
            const float4v v4 = *(const float4v*)&sb[dxs * 16 + mq * 4];
            *(float4v*)&out[((((size_t)b * 81) + r * ND + dxs) * H_ + y0) * W_
                            + X0 + mq * 4] = v4;
        }
    }
    // ---- extraction pass 2: y0+1 ----
    #pragma unroll
    for (int r = 0; r < ND; ++r) {
        const int row = y0 + 1 + r - MD;
        const bool liv = (0 <= row && row < H_);
        #pragma unroll
        for (int i = 0; i < 4; ++i) {
            sw[(kg * 4 + i) * 36 + ln]      = aB0[r][i];
            sw[(kg * 4 + i) * 36 + 16 + ln] = aB1[r][i];
        }
        #pragma unroll
        for (int i = 0; i < 3; ++i) {
            const int dx = i * 4 + kg;
            if (dx < ND) {
                const float v = liv ? sw[ln * 36 + ln + dx + 4] * scale : 0.0f;
                sb[dx * 16 + ln] = v;
            }
        }
        if (l < 36) {
            const int dxs = l >> 2, mq = l & 3;
            const float4v v4 = *(const float4v*)&sb[dxs * 16 + mq * 4];
            *(float4v*)&out[((((size_t)b * 81) + r * ND + dxs) * H_ + (y0 + 1)) * W_
                            + X0 + mq * 4] = v4;
        }
    }
}

// ---- fallback: proven 76us scalar kernel (R11) if ws too small ----
__global__ __launch_bounds__(9 * 64, 3)
void corr_fallback(const float* __restrict__ t1,
                   const float* __restrict__ t2,
                   float* __restrict__ out) {
    const int tid  = threadIdx.x;
    const int lane = tid & 63;
    const int w    = tid >> 6;
    const int bid  = blockIdx.x;
    const int swz  = (bid & 7) * 32 + (bid >> 3);
    const int yp   = swz & 63;
    const int b    = swz >> 6;
    const int y0   = yp * 2;
    const int half = lane >> 5;
    const int lx   = lane & 31;
    const int x0   = lx * 8;
    const int yrow = y0 + half;
    const int yy   = yrow + w - MD;
    const bool live = (0 <= yy) && (yy < H_);
    const int  yc  = yy < 0 ? 0 : (yy > H_ - 1 ? H_ - 1 : yy);
    const float sc = live ? (1.0f / (float)C_) : 0.0f;
    const bool lm  = (lx == 0);
    const bool rm  = (lx == 31);
    const int offL = lm ? 0 : -4;
    const int offR = rm ? 0 :  8;

    float acc[ND][8];
    #pragma unroll
    for (int dx = 0; dx < ND; ++dx)
        #pragma unroll
        for (int j = 0; j < 8; ++j) acc[dx][j] = 0.0f;

    const float* p1 = t1 + (((size_t)(b * C_)) * H_ + yrow) * W_ + x0;
    const float* p2 = t2 + (((size_t)(b * C_)) * H_ + yc  ) * W_ + x0;
    const size_t chstr = (size_t)H_ * W_;

    #pragma unroll 2
    for (int c = 0; c < C_; ++c) {
        const float* pc1 = p1 + (size_t)c * chstr;
        const float* pc2 = p2 + (size_t)c * chstr;
        const float4v a0 = *(const float4v*)(pc1);
        const float4v a1 = *(const float4v*)(pc1 + 4);
        float4v wl = *(const float4v*)(pc2 + offL);
        const float4v v0 = *(const float4v*)(pc2);
        const float4v v1 = *(const float4v*)(pc2 + 4);
        float4v wr = *(const float4v*)(pc2 + offR);
        #pragma unroll
        for (int qq = 0; qq < 4; ++qq) {
            wl[qq] = lm ? 0.0f : wl[qq];
            wr[qq] = rm ? 0.0f : wr[qq];
        }
        float win[16];
        #pragma unroll
        for (int qq = 0; qq < 4; ++qq) {
            win[qq] = wl[qq]; win[4 + qq] = v0[qq];
            win[8 + qq] = v1[qq]; win[12 + qq] = wr[qq];
        }
        #pragma unroll
        for (int dx = 0; dx < ND; ++dx)
            #pragma unroll
            for (int j = 0; j < 8; ++j) {
                const float aj = (j < 4) ? a0[j] : a1[j - 4];
                acc[dx][j] = fmaf(aj, win[dx + j], acc[dx][j]);
            }
    }

    #pragma unroll
    for (int dx = 0; dx < ND; ++dx) {
        float4v o0, o1;
        #pragma unroll
        for (int j = 0; j < 4; ++j) {
            o0[j] = acc[dx][j] * sc;
            o1[j] = acc[dx][4 + j] * sc;
        }
        const size_t oidx =
            (((size_t)(b * ND * ND) + w * ND + dx) * H_ + yrow) * W_ + x0;
        *(float4v*)&out[oidx]     = o0;
        *(float4v*)&out[oidx + 4] = o1;
    }
}

extern "C" void kernel_launch(void* const* d_in, const int* in_sizes, int n_in,
                              void* d_out, int out_size, void* d_ws, size_t ws_size,
                              hipStream_t stream) {
    const float* t1 = (const float*)d_in[0];
    const float* t2 = (const float*)d_in[1];
    float* out      = (float*)d_out;
    const size_t need = TS * sizeof(unsigned short);   // 33.5 MB (t2 only)
    if (ws_size >= need) {
        unsigned short* ws = (unsigned short*)d_ws;
        convert_one<<<dim3(B_ * H_ * 4), 256, 0, stream>>>(t2, ws);
        corr_mfma9 <<<dim3(B_ * H_), 512, 0, stream>>>(t1, ws, out);
    } else {
        corr_fallback<<<dim3(B_ * H_ / 2), 9 * 64, 0, stream>>>(t1, t2, out);
    }
}